// Round 15
// baseline (1595.288 us; speedup 1.0000x reference)
//
#include <hip/hip_runtime.h>
#include <hip/hip_cooperative_groups.h>
#include <hip/hip_bf16.h>
#include <math.h>

namespace cg = cooperative_groups;

#define Nn 10000
#define Ee 160000
#define ET 170000   // Ee + Nn (self loops)
#define LL 6

typedef short v8s __attribute__((ext_vector_type(8)));
typedef float v4f __attribute__((ext_vector_type(4)));
typedef float v2f __attribute__((ext_vector_type(2)));

__device__ __forceinline__ unsigned short f2bf(float v) {
    unsigned int b = __float_as_uint(v);
    b += 0x7fffu + ((b >> 16) & 1u);   // RNE
    return (unsigned short)(b >> 16);
}
__device__ __forceinline__ float bflo(unsigned int u) { return __uint_as_float(u << 16); }
__device__ __forceinline__ float bfhi(unsigned int u) { return __uint_as_float(u & 0xffff0000u); }

// ---------------- node embedding ----------------
__global__ void k_node_embed(const float* __restrict__ x, const float* __restrict__ nw,
                             const float* __restrict__ nb, float* __restrict__ h,
                             unsigned short* __restrict__ hb) {
    int idx = blockIdx.x * 256 + threadIdx.x;
    if (idx >= Nn * 128) return;
    int n = idx >> 7, c = idx & 127;
    const float* xr = x + (size_t)n * 8;
    float acc = nb[c];
#pragma unroll
    for (int k = 0; k < 8; k++) acc += xr[k] * nw[k * 128 + c];
    h[idx] = acc;
    hb[idx] = f2bf(acc);
}

// ---------------- small precompute: E1 ----------------
__global__ void k_small(const float* __restrict__ vnfc, const float* __restrict__ vw,
                        const float* __restrict__ vb, const float* __restrict__ eab,
                        const float* __restrict__ a1w, const float* __restrict__ a1b,
                        const float* __restrict__ eaw, float* __restrict__ E1) {
    __shared__ float vr[128];
    __shared__ float sM1[512];
    __shared__ float sd1[128];
    int t = threadIdx.x;   // 512
    if (t < 128) {
        float a = vb[t];
#pragma unroll
        for (int k = 0; k < 6; k++) a += vnfc[k] * vw[k * 128 + t];
        vr[t] = a;
    }
    __syncthreads();
    if (t < 128) {
        float a = a1b[t];
        for (int k = 0; k < 128; k++) a += eab[k] * a1w[k * 128 + t];
        for (int k = 0; k < 128; k++) a += vr[k] * a1w[(128 + k) * 128 + t];
        sd1[t] = a;
    }
    {
        int r = t >> 7, j = t & 127;
        float a = 0.f;
        for (int k = 0; k < 128; k++) a += eaw[r * 128 + k] * a1w[k * 128 + j];
        sM1[r * 128 + j] = a;
    }
    __syncthreads();
    if (t < 128) {
        E1[t * 8 + 0] = sM1[t];
        E1[t * 8 + 1] = sM1[128 + t];
        E1[t * 8 + 2] = sM1[256 + t];
        E1[t * 8 + 3] = sM1[384 + t];
        E1[t * 8 + 4] = sd1[t];
        E1[t * 8 + 5] = 0.f; E1[t * 8 + 6] = 0.f; E1[t * 8 + 7] = 0.f;
    }
}

// ---------------- B matrices ----------------
__global__ void k_bmat(const float* __restrict__ glw, const float* __restrict__ gas,
                       const float* __restrict__ gad, const float* __restrict__ glew,
                       const float* __restrict__ gae, float* __restrict__ Bs,
                       float* __restrict__ Bd, float* __restrict__ Be) {
    int idx = blockIdx.x * 256 + threadIdx.x;
    if (idx >= LL * 128 * 4) return;
    int hh = idx & 3, k = (idx >> 2) & 127, l = idx >> 9;
    const float* lwp = glw  + (size_t)l * 65536 + k * 512 + hh * 128;
    const float* lep = glew + (size_t)l * 65536 + k * 512 + hh * 128;
    const float* sp = gas + l * 512 + hh * 128;
    const float* dp = gad + l * 512 + hh * 128;
    const float* ep = gae + l * 512 + hh * 128;
    float s1 = 0, s2 = 0, s3 = 0;
    for (int c = 0; c < 128; c++) {
        float lv = lwp[c];
        s1 += lv * sp[c];
        s2 += lv * dp[c];
        s3 += lep[c] * ep[c];
    }
    Bs[idx] = s1; Bd[idx] = s2; Be[idx] = s3;
}

// ---- WsumT[l][c][kk] bf16 = 0.25 * lw_l[kk&127][ (kk>>7)*128 + c ] ----
__global__ void k_wsum(const float* __restrict__ glw, unsigned short* __restrict__ WsumT) {
    int idx = blockIdx.x * 256 + threadIdx.x;
    if (idx >= LL * 128 * 512) return;
    int kk = idx & 511;
    int c = (idx >> 9) & 127;
    int l = idx >> 16;
    float v = 0.25f * glw[(size_t)l * 65536 + (size_t)(kk & 127) * 512 + (kk >> 7) * 128 + c];
    WsumT[(size_t)l * 65536 + (size_t)c * 512 + kk] = f2bf(v);
}

// ---------------- PB/cB ----------------
__global__ void k_pb(const float* __restrict__ eaw, const float* __restrict__ eab,
                     const float* __restrict__ Be, float* __restrict__ PB,
                     float* __restrict__ cB) {
    int t = threadIdx.x;
    if (t >= 24) return;
    int l = t >> 2, hh = t & 3;
    const float* bp = Be + l * 512 + hh;
    float s0 = 0, s1 = 0, s2 = 0, s3 = 0, sc = 0;
    for (int k = 0; k < 128; k++) {
        float bv = bp[k * 4];
        s0 += eaw[0 * 128 + k] * bv;
        s1 += eaw[1 * 128 + k] * bv;
        s2 += eaw[2 * 128 + k] * bv;
        s3 += eaw[3 * 128 + k] * bv;
        sc += eab[k] * bv;
    }
    PB[0 * 24 + t] = s0; PB[1 * 24 + t] = s1;
    PB[2 * 24 + t] = s2; PB[3 * 24 + t] = s3;
    cB[t] = sc;
}

// ---- edge gate MLP (R13-proven): 256 thr, 4 edges/lane ----
__global__ __launch_bounds__(256, 3) void k_edge(
    const float* __restrict__ ea, const float* __restrict__ E1,
    const float* __restrict__ a2w, const float* __restrict__ a2b,
    const float* __restrict__ a3w, const float* __restrict__ a3b,
    float* __restrict__ Gg, float4* __restrict__ Ge4, float* __restrict__ gsum) {
    __shared__ float sw2[128 * 64];
    __shared__ float4 sM[128];
    __shared__ float sD[128];
    __shared__ float prs[4][256];
    __shared__ float gsh[256];
    int t = threadIdx.x;
    int lane = t & 63;
    int p = t >> 6;
    int ps = __builtin_amdgcn_readfirstlane(p);
    for (int z = t; z < 2048; z += 256) ((float4*)sw2)[z] = ((const float4*)a2w)[z];
    if (t < 128) { sM[t] = *(const float4*)(E1 + t * 8); sD[t] = E1[t * 8 + 4]; }
    __syncthreads();
    int eb = blockIdx.x * 256 + lane;
    float4 ev[4];
#pragma unroll
    for (int r = 0; r < 4; r++) ev[r] = *(const float4*)(ea + (size_t)(eb + r * 64) * 4);
    v2f acc[4][8];
#pragma unroll
    for (int j = 0; j < 8; j++) {
        v2f b = {a2b[ps * 16 + 2 * j], a2b[ps * 16 + 2 * j + 1]};
#pragma unroll
        for (int r = 0; r < 4; r++) acc[r][j] = b;
    }
    const float* w2base = sw2 + ps * 16;
    for (int k = 0; k < 128; k++) {
        float4 m = sM[k];
        float dk = sD[k];
        v2f xx[4];
#pragma unroll
        for (int r = 0; r < 4; r++) {
            float xv = fmaxf(dk + ev[r].x * m.x + ev[r].y * m.y + ev[r].z * m.z + ev[r].w * m.w, 0.f);
            xx[r][0] = xv; xx[r][1] = xv;
        }
        const float* w2r = w2base + k * 64;
#pragma unroll
        for (int j4 = 0; j4 < 4; j4++) {
            float4 wv = *(const float4*)(w2r + j4 * 4);
            v2f w01 = {wv.x, wv.y}, w23 = {wv.z, wv.w};
#pragma unroll
            for (int r = 0; r < 4; r++) {
                acc[r][2 * j4]     += xx[r] * w01;
                acc[r][2 * j4 + 1] += xx[r] * w23;
            }
        }
    }
#pragma unroll
    for (int r = 0; r < 4; r++) {
        float pr = 0.f;
#pragma unroll
        for (int j = 0; j < 8; j++) {
            pr += fmaxf(acc[r][j][0], 0.f) * a3w[ps * 16 + 2 * j];
            pr += fmaxf(acc[r][j][1], 0.f) * a3w[ps * 16 + 2 * j + 1];
        }
        prs[p][r * 64 + lane] = pr;
    }
    __syncthreads();
    if (p == 0) {
        float v0 = 0.f, v1 = 0.f, v2 = 0.f, v3 = 0.f, v4 = 0.f;
#pragma unroll
        for (int rep = 0; rep < 4; rep++) {
            int le = rep * 64 + lane;
            float tot = prs[0][le] + prs[1][le] + prs[2][le] + prs[3][le] + a3b[0];
            float g = 1.f / (1.f + __expf(-tot));
            gsh[le] = g;
            float4 evv = ev[rep];
            v0 += g; v1 += g * evv.x; v2 += g * evv.y; v3 += g * evv.z; v4 += g * evv.w;
        }
#pragma unroll
        for (int d = 32; d > 0; d >>= 1) {
            v0 += __shfl_down(v0, d); v1 += __shfl_down(v1, d); v2 += __shfl_down(v2, d);
            v3 += __shfl_down(v3, d); v4 += __shfl_down(v4, d);
        }
        if (lane == 0) {
            atomicAdd(&gsum[0], v0); atomicAdd(&gsum[1], v1); atomicAdd(&gsum[2], v2);
            atomicAdd(&gsum[3], v3); atomicAdd(&gsum[4], v4);
        }
    }
    __syncthreads();
    {
        int e = blockIdx.x * 256 + ps * 64 + lane;
        float g = gsh[ps * 64 + lane];
        float4 evv = *(const float4*)(ea + (size_t)e * 4);
        Gg[e] = g;
        Ge4[e] = make_float4(g * evv.x, g * evv.y, g * evv.z, g * evv.w);
    }
}

// ---------------- counting sort: hist / scan / scatter ----------------
__global__ void k_hist(const int* __restrict__ ei, int* __restrict__ hist) {
    int i = blockIdx.x * 256 + threadIdx.x;
    if (i >= ET) return;
    int d = (i < Ee) ? ei[Ee + i] : (i - Ee);
    atomicAdd(&hist[d], 1);
}

__global__ __launch_bounds__(1024) void k_scan(const int* __restrict__ hist,
                                               int* __restrict__ seg, int* __restrict__ pos) {
    __shared__ int wsums[16];
    __shared__ int carry_s;
    int t = threadIdx.x;
    int lane = t & 63, wid = t >> 6;
    if (t == 0) { carry_s = 0; seg[0] = 0; }
    __syncthreads();
    for (int base = 0; base < Nn; base += 1024) {
        int idx = base + t;
        int v = (idx < Nn) ? hist[idx] : 0;
        int sc = v;
#pragma unroll
        for (int d = 1; d < 64; d <<= 1) {
            int up = __shfl_up(sc, d);
            if (lane >= d) sc += up;
        }
        if (lane == 63) wsums[wid] = sc;
        __syncthreads();
        if (wid == 0) {
            int wv = (lane < 16) ? wsums[lane] : 0;
            int wsc = wv;
#pragma unroll
            for (int d = 1; d < 16; d <<= 1) {
                int up = __shfl_up(wsc, d);
                if (lane >= d) wsc += up;
            }
            if (lane < 16) wsums[lane] = wsc - wv;
        }
        __syncthreads();
        int carry = carry_s;
        int inc = sc + wsums[wid] + carry;
        if (idx < Nn) { seg[idx + 1] = inc; pos[idx] = inc - v; }
        __syncthreads();
        if (t == 1023) carry_s = inc;
        __syncthreads();
    }
}

__global__ void k_scatter(const int* __restrict__ ei, int* __restrict__ pos,
                          int2* __restrict__ pse) {
    int i = blockIdx.x * 256 + threadIdx.x;
    if (i >= ET) return;
    int s, d;
    if (i < Ee) { s = ei[i]; d = ei[Ee + i]; } else { s = d = i - Ee; }
    int idx = atomicAdd(&pos[d], 1);
    pse[idx] = make_int2(s, i);
}

// ---- aleS[l][i] (sorted order, all layers) ----
__global__ void k_ales(const int2* __restrict__ pse, const float* __restrict__ Gg,
                       const float4* __restrict__ Ge4, const float* __restrict__ gsum,
                       const float* __restrict__ PB, const float* __restrict__ cB,
                       float4* __restrict__ aleS) {
    int i = blockIdx.x * 256 + threadIdx.x;
    if (i >= ET) return;
    int y = pse[i].y;
    float g;
    float4 ge;
    if (y < Ee) { g = Gg[y]; ge = Ge4[y]; }
    else {
        float inv = 1.f / Ee;
        g = gsum[0] * inv;
        ge = make_float4(gsum[1] * inv, gsum[2] * inv, gsum[3] * inv, gsum[4] * inv);
    }
#pragma unroll
    for (int l = 0; l < LL; l++) {
        float4 o;
        o.x = g * cB[l * 4 + 0] + ge.x * PB[0 * 24 + l * 4 + 0] + ge.y * PB[1 * 24 + l * 4 + 0]
            + ge.z * PB[2 * 24 + l * 4 + 0] + ge.w * PB[3 * 24 + l * 4 + 0];
        o.y = g * cB[l * 4 + 1] + ge.x * PB[0 * 24 + l * 4 + 1] + ge.y * PB[1 * 24 + l * 4 + 1]
            + ge.z * PB[2 * 24 + l * 4 + 1] + ge.w * PB[3 * 24 + l * 4 + 1];
        o.z = g * cB[l * 4 + 2] + ge.x * PB[0 * 24 + l * 4 + 2] + ge.y * PB[1 * 24 + l * 4 + 2]
            + ge.z * PB[2 * 24 + l * 4 + 2] + ge.w * PB[3 * 24 + l * 4 + 2];
        o.w = g * cB[l * 4 + 3] + ge.x * PB[0 * 24 + l * 4 + 3] + ge.y * PB[1 * 24 + l * 4 + 3]
            + ge.z * PB[2 * 24 + l * 4 + 3] + ge.w * PB[3 * 24 + l * 4 + 3];
        aleS[(size_t)l * ET + i] = o;
    }
}

// ---------------- layer-0: als/ald ----------------
__global__ void k_ab(const float* __restrict__ h, const float* __restrict__ Bs_l,
                     const float* __restrict__ Bd_l, float* __restrict__ als,
                     float* __restrict__ ald) {
    int idx = blockIdx.x * 256 + threadIdx.x;
    if (idx >= Nn * 8) return;
    int n = idx >> 3, slot = idx & 7;
    const float* B = (slot < 4) ? Bs_l : Bd_l;
    int hh = slot & 3;
    const float4* hr = (const float4*)(h + (size_t)n * 128);
    float s = 0.f;
#pragma unroll 8
    for (int kb = 0; kb < 32; kb++) {
        float4 hv = hr[kb];
        s += hv.x * B[(4 * kb + 0) * 4 + hh] + hv.y * B[(4 * kb + 1) * 4 + hh]
           + hv.z * B[(4 * kb + 2) * 4 + hh] + hv.w * B[(4 * kb + 3) * 4 + hh];
    }
    if (slot < 4) als[n * 4 + hh] = s;
    else          ald[n * 4 + hh] = s;
}

// ==== COOPERATIVE: full layer loop (agg -> sync -> post -> sync) x6 -> out ====
__global__ __launch_bounds__(256) void k_loop(
    const int2* __restrict__ pse, const int* __restrict__ seg,
    float* __restrict__ als, float* __restrict__ ald,
    const float4* __restrict__ aleS, unsigned short* __restrict__ hb,
    unsigned short* __restrict__ aggb, const unsigned short* __restrict__ WsumT,
    const float* __restrict__ gball, const float* __restrict__ lnscall,
    const float* __restrict__ lnbiall, float* __restrict__ h,
    const float* __restrict__ Bs, const float* __restrict__ Bd,
    const float* __restrict__ ow, const float* __restrict__ ob,
    float* __restrict__ out) {
    __shared__ float smem[1664];   // 6656 B, reused per phase
    cg::grid_group grid = cg::this_grid();
    int t = threadIdx.x;
    int lane = t & 63;
    int w4 = t >> 6;
    for (int l = 0; l < LL; l++) {
        // ---------- agg phase: 4 waves/node, grid-stride ----------
        const float4* aleS_l = aleS + (size_t)l * ET;
        float* part = smem;          // [3][512]
        float* pden = smem + 1536;   // [3][4]
        for (int n = blockIdx.x; n < Nn; n += gridDim.x) {
            int start = seg[n], end = seg[n + 1];
            int deg = end - start;
            int quarter = (deg + 3) >> 2;
            int s0 = start + w4 * quarter;
            int e0 = min(s0 + quarter, end);
            int hp = lane >> 4;
            int cch = (lane & 15) * 8;
            float aldh = ald[n * 4 + hp];
            float den = 0.f;
            float4 acc0 = make_float4(0.f, 0.f, 0.f, 0.f);
            float4 acc1 = make_float4(0.f, 0.f, 0.f, 0.f);
            int i = s0;
            for (; i + 2 <= e0; i += 2) {
                int sa = pse[i].x, sb = pse[i + 1].x;
                float4 ala4 = aleS_l[i], alb4 = aleS_l[i + 1];
                float ala = hp == 0 ? ala4.x : hp == 1 ? ala4.y : hp == 2 ? ala4.z : ala4.w;
                float alb = hp == 0 ? alb4.x : hp == 1 ? alb4.y : hp == 2 ? alb4.z : alb4.w;
                float ava = als[sa * 4 + hp] + aldh + ala;
                float avb = als[sb * 4 + hp] + aldh + alb;
                ava = ava > 0.f ? ava : 0.2f * ava;
                avb = avb > 0.f ? avb : 0.2f * avb;
                float ea = __expf(fminf(ava, 60.f));
                float eb = __expf(fminf(avb, 60.f));
                den += ea + eb;
                uint4 ua = *(const uint4*)(hb + (size_t)sa * 128 + cch);
                uint4 ub = *(const uint4*)(hb + (size_t)sb * 128 + cch);
                acc0.x += ea * bflo(ua.x) + eb * bflo(ub.x);
                acc0.y += ea * bfhi(ua.x) + eb * bfhi(ub.x);
                acc0.z += ea * bflo(ua.y) + eb * bflo(ub.y);
                acc0.w += ea * bfhi(ua.y) + eb * bfhi(ub.y);
                acc1.x += ea * bflo(ua.z) + eb * bflo(ub.z);
                acc1.y += ea * bfhi(ua.z) + eb * bfhi(ub.z);
                acc1.z += ea * bflo(ua.w) + eb * bflo(ub.w);
                acc1.w += ea * bfhi(ua.w) + eb * bfhi(ub.w);
            }
            if (i < e0) {
                int sa = pse[i].x;
                float4 ala4 = aleS_l[i];
                float ala = hp == 0 ? ala4.x : hp == 1 ? ala4.y : hp == 2 ? ala4.z : ala4.w;
                float ava = als[sa * 4 + hp] + aldh + ala;
                ava = ava > 0.f ? ava : 0.2f * ava;
                float ea = __expf(fminf(ava, 60.f));
                den += ea;
                uint4 ua = *(const uint4*)(hb + (size_t)sa * 128 + cch);
                acc0.x += ea * bflo(ua.x); acc0.y += ea * bfhi(ua.x);
                acc0.z += ea * bflo(ua.y); acc0.w += ea * bfhi(ua.y);
                acc1.x += ea * bflo(ua.z); acc1.y += ea * bfhi(ua.z);
                acc1.z += ea * bflo(ua.w); acc1.w += ea * bfhi(ua.w);
            }
            if (w4 > 0) {
                *(float4*)&part[(w4 - 1) * 512 + lane * 8] = acc0;
                *(float4*)&part[(w4 - 1) * 512 + lane * 8 + 4] = acc1;
                if ((lane & 15) == 0) pden[(w4 - 1) * 4 + hp] = den;
            }
            __syncthreads();
            if (w4 == 0) {
                float dtot = den + pden[0 * 4 + hp] + pden[1 * 4 + hp] + pden[2 * 4 + hp];
#pragma unroll
                for (int r = 0; r < 3; r++) {
                    float4 p0 = *(const float4*)&part[r * 512 + lane * 8];
                    float4 p1 = *(const float4*)&part[r * 512 + lane * 8 + 4];
                    acc0.x += p0.x; acc0.y += p0.y; acc0.z += p0.z; acc0.w += p0.w;
                    acc1.x += p1.x; acc1.y += p1.y; acc1.z += p1.z; acc1.w += p1.w;
                }
                float inv = 1.f / (dtot + 1e-16f);
                acc0.x *= inv; acc0.y *= inv; acc0.z *= inv; acc0.w *= inv;
                acc1.x *= inv; acc1.y *= inv; acc1.z *= inv; acc1.w *= inv;
                ushort4 q0, q1;
                q0.x = f2bf(acc0.x); q0.y = f2bf(acc0.y); q0.z = f2bf(acc0.z); q0.w = f2bf(acc0.w);
                q1.x = f2bf(acc1.x); q1.y = f2bf(acc1.y); q1.z = f2bf(acc1.z); q1.w = f2bf(acc1.w);
                *(ushort4*)(aggb + (size_t)n * 512 + lane * 8) = q0;
                *(ushort4*)(aggb + (size_t)n * 512 + lane * 8 + 4) = q1;
            }
            __syncthreads();
        }
        __threadfence();
        grid.sync();
        // ---------- post phase: 4 waves share a 16-node tile, grid-stride ----------
        const unsigned short* W_l = WsumT + (size_t)l * 65536;
        const float* gbias = gball + l * 128;
        const float* ls = lnscall + l * 128;
        const float* lb = lnbiall + l * 128;
        int ln = (l + 1) % LL;
        const float* Bs_n = Bs + ln * 512;
        const float* Bd_n = Bd + ln * 512;
        float* sred1 = smem;          // [4][16]
        float* sred2 = smem + 64;     // [4][16]
        float* sA    = smem + 128;    // [4][16][4]
        float* sDd   = smem + 384;    // [4][16][4]
        for (int tile = blockIdx.x; tile < Nn / 16; tile += gridDim.x) {
            int n0 = tile * 16;
            int m = lane & 15, q = lane >> 4;
            v4f accv[2];
            accv[0] = (v4f){0.f, 0.f, 0.f, 0.f};
            accv[1] = (v4f){0.f, 0.f, 0.f, 0.f};
            const unsigned short* arow = aggb + (size_t)(n0 + m) * 512 + q * 8;
            int col0 = (2 * w4) * 16 + m, col1 = col0 + 16;
#pragma unroll 4
            for (int ks = 0; ks < 16; ks++) {
                v8s fa = *(const v8s*)(arow + ks * 32);
                v8s fb0 = *(const v8s*)(W_l + (size_t)col0 * 512 + ks * 32 + q * 8);
                v8s fb1 = *(const v8s*)(W_l + (size_t)col1 * 512 + ks * 32 + q * 8);
                accv[0] = __builtin_amdgcn_mfma_f32_16x16x32_bf16(fa, fb0, accv[0], 0, 0, 0);
                accv[1] = __builtin_amdgcn_mfma_f32_16x16x32_bf16(fa, fb1, accv[1], 0, 0, 0);
            }
            float v[2][4];
            float s1[4] = {0.f, 0.f, 0.f, 0.f}, s2[4] = {0.f, 0.f, 0.f, 0.f};
#pragma unroll
            for (int j = 0; j < 2; j++) {
                int col = j == 0 ? col0 : col1;
                float b = gbias[col];
#pragma unroll
                for (int r = 0; r < 4; r++) {
                    int row = n0 + q * 4 + r;
                    float val = h[(size_t)row * 128 + col] + fmaxf(accv[j][r] + b, 0.f);
                    v[j][r] = val;
                    s1[r] += val; s2[r] += val * val;
                }
            }
#pragma unroll
            for (int d = 1; d <= 8; d <<= 1) {
#pragma unroll
                for (int r = 0; r < 4; r++) {
                    s1[r] += __shfl_xor(s1[r], d);
                    s2[r] += __shfl_xor(s2[r], d);
                }
            }
            if (m == 0) {
#pragma unroll
                for (int r = 0; r < 4; r++) {
                    sred1[w4 * 16 + q * 4 + r] = s1[r];
                    sred2[w4 * 16 + q * 4 + r] = s2[r];
                }
            }
            __syncthreads();
            float o2[2][4];
#pragma unroll
            for (int r = 0; r < 4; r++) {
                int row = q * 4 + r;
                float t1 = sred1[row] + sred1[16 + row] + sred1[32 + row] + sred1[48 + row];
                float t2 = sred2[row] + sred2[16 + row] + sred2[32 + row] + sred2[48 + row];
                float mean = t1 * (1.f / 128.f);
                float var = t2 * (1.f / 128.f) - mean * mean;
                float rinv = rsqrtf(var + 1e-5f);
                int grow = n0 + row;
#pragma unroll
                for (int j = 0; j < 2; j++) {
                    int col = j == 0 ? col0 : col1;
                    float o = (v[j][r] - mean) * rinv * ls[col] + lb[col];
                    o2[j][r] = o;
                    h[(size_t)grow * 128 + col] = o;
                    hb[(size_t)grow * 128 + col] = f2bf(o);
                }
            }
            float sal[4][4], sad[4][4];
#pragma unroll
            for (int r = 0; r < 4; r++)
#pragma unroll
                for (int hh = 0; hh < 4; hh++) { sal[r][hh] = 0.f; sad[r][hh] = 0.f; }
#pragma unroll
            for (int j = 0; j < 2; j++) {
                int col = j == 0 ? col0 : col1;
                float4 bs = *(const float4*)(Bs_n + col * 4);
                float4 bd = *(const float4*)(Bd_n + col * 4);
#pragma unroll
                for (int r = 0; r < 4; r++) {
                    float o = o2[j][r];
                    sal[r][0] += o * bs.x; sal[r][1] += o * bs.y;
                    sal[r][2] += o * bs.z; sal[r][3] += o * bs.w;
                    sad[r][0] += o * bd.x; sad[r][1] += o * bd.y;
                    sad[r][2] += o * bd.z; sad[r][3] += o * bd.w;
                }
            }
#pragma unroll
            for (int d = 1; d <= 8; d <<= 1) {
#pragma unroll
                for (int r = 0; r < 4; r++)
#pragma unroll
                    for (int hh = 0; hh < 4; hh++) {
                        sal[r][hh] += __shfl_xor(sal[r][hh], d);
                        sad[r][hh] += __shfl_xor(sad[r][hh], d);
                    }
            }
            if (m == 0) {
#pragma unroll
                for (int r = 0; r < 4; r++)
#pragma unroll
                    for (int hh = 0; hh < 4; hh++) {
                        sA[w4 * 64 + (q * 4 + r) * 4 + hh] = sal[r][hh];
                        sDd[w4 * 64 + (q * 4 + r) * 4 + hh] = sad[r][hh];
                    }
            }
            __syncthreads();
            if (t < 128) {
                int row = t >> 3, slot = t & 7, hh = slot & 3;
                if (slot < 4) {
                    float va = sA[row * 4 + hh] + sA[64 + row * 4 + hh]
                             + sA[128 + row * 4 + hh] + sA[192 + row * 4 + hh];
                    als[(n0 + row) * 4 + hh] = va;
                } else {
                    float vd = sDd[row * 4 + hh] + sDd[64 + row * 4 + hh]
                             + sDd[128 + row * 4 + hh] + sDd[192 + row * 4 + hh];
                    ald[(n0 + row) * 4 + hh] = vd;
                }
            }
            __syncthreads();
        }
        __threadfence();
        grid.sync();
    }
    // ---------- output projection ----------
    float4* hs4 = (float4*)smem;   // [8][32]
    for (int tile = blockIdx.x; tile < Nn / 8; tile += gridDim.x) {
        int n0 = tile * 8;
        {
            int i = t >> 5, kb = t & 31;
            hs4[i * 32 + kb] = *(const float4*)(h + (size_t)(n0 + i) * 128 + 4 * kb);
        }
        __syncthreads();
        float acc[8] = {0, 0, 0, 0, 0, 0, 0, 0};
        for (int kb = 0; kb < 32; kb++) {
            float w0 = ow[(4 * kb + 0) * 256 + t];
            float w1 = ow[(4 * kb + 1) * 256 + t];
            float w2 = ow[(4 * kb + 2) * 256 + t];
            float w3 = ow[(4 * kb + 3) * 256 + t];
#pragma unroll
            for (int i = 0; i < 8; i++) {
                float4 hv = hs4[i * 32 + kb];
                acc[i] += hv.x * w0 + hv.y * w1 + hv.z * w2 + hv.w * w3;
            }
        }
        float b = ob[t];
#pragma unroll
        for (int i = 0; i < 8; i++) out[(size_t)(n0 + i) * 256 + t] = acc[i] + b;
        __syncthreads();
    }
}

extern "C" void kernel_launch(void* const* d_in, const int* in_sizes, int n_in,
                              void* d_out, int out_size, void* d_ws, size_t ws_size,
                              hipStream_t stream) {
    const float* x    = (const float*)d_in[0];
    const int*   ei   = (const int*)d_in[1];
    const float* ea   = (const float*)d_in[2];
    const float* vnfc = (const float*)d_in[3];
    const float* nw   = (const float*)d_in[4];
    const float* nb   = (const float*)d_in[5];
    const float* eaw  = (const float*)d_in[6];
    const float* eab  = (const float*)d_in[7];
    const float* vw   = (const float*)d_in[8];
    const float* vb   = (const float*)d_in[9];
    const float* a1w  = (const float*)d_in[10];
    const float* a1b  = (const float*)d_in[11];
    const float* a2w  = (const float*)d_in[12];
    const float* a2b  = (const float*)d_in[13];
    const float* a3w  = (const float*)d_in[14];
    const float* a3b  = (const float*)d_in[15];
    const float* glw  = (const float*)d_in[16];
    const float* gas  = (const float*)d_in[17];
    const float* gad  = (const float*)d_in[18];
    const float* glew = (const float*)d_in[19];
    const float* gae  = (const float*)d_in[20];
    const float* gb   = (const float*)d_in[21];
    const float* lnsc = (const float*)d_in[22];
    const float* lnbi = (const float*)d_in[23];
    const float* ow   = (const float*)d_in[24];
    const float* ob   = (const float*)d_in[25];
    float* out = (float*)d_out;

    char* w = (char*)d_ws;
    size_t o = 0;
    auto allocf = [&](size_t cnt) { float* p = (float*)(w + o); o += ((cnt * 4 + 255) / 256) * 256; return p; };
    auto alloci = [&](size_t cnt) { int* p = (int*)(w + o); o += ((cnt * 4 + 255) / 256) * 256; return p; };
    auto allocu = [&](size_t cnt) { unsigned short* p = (unsigned short*)(w + o); o += ((cnt * 2 + 255) / 256) * 256; return p; };
    float* h      = allocf((size_t)Nn * 128);
    unsigned short* hb    = allocu((size_t)Nn * 128);
    unsigned short* aggb  = allocu((size_t)Nn * 512);
    unsigned short* WsumT = allocu((size_t)LL * 128 * 512);
    float* als    = allocf((size_t)Nn * 4);
    float* ald    = allocf((size_t)Nn * 4);
    float* Gg     = allocf((size_t)Ee);
    float4* Ge4   = (float4*)allocf((size_t)Ee * 4);
    float4* aleS  = (float4*)allocf((size_t)LL * ET * 4);
    float* Bs     = allocf(3072);
    float* Bd     = allocf(3072);
    float* Be     = allocf(3072);
    float* E1     = allocf(1024);
    float* PB     = allocf(96);
    float* cB     = allocf(24);
    float* gsum   = allocf(8);
    int* seg  = alloci(Nn + 1);
    int* hist = alloci(Nn);
    int* pos  = alloci(Nn);
    int2* pse = (int2*)alloci((size_t)ET * 2);

    hipMemsetAsync(hist, 0, Nn * sizeof(int), stream);
    hipMemsetAsync(gsum, 0, 8 * sizeof(float), stream);

    k_node_embed<<<(Nn * 128 + 255) / 256, 256, 0, stream>>>(x, nw, nb, h, hb);
    k_small<<<1, 512, 0, stream>>>(vnfc, vw, vb, eab, a1w, a1b, eaw, E1);
    k_bmat<<<(LL * 128 * 4 + 255) / 256, 256, 0, stream>>>(glw, gas, gad, glew, gae, Bs, Bd, Be);
    k_wsum<<<(LL * 128 * 512 + 255) / 256, 256, 0, stream>>>(glw, WsumT);
    k_pb<<<1, 32, 0, stream>>>(eaw, eab, Be, PB, cB);
    k_edge<<<Ee / 256, 256, 0, stream>>>(ea, E1, a2w, a2b, a3w, a3b, Gg, Ge4, gsum);
    k_hist<<<(ET + 255) / 256, 256, 0, stream>>>(ei, hist);
    k_scan<<<1, 1024, 0, stream>>>(hist, seg, pos);
    k_scatter<<<(ET + 255) / 256, 256, 0, stream>>>(ei, pos, pse);
    k_ales<<<(ET + 255) / 256, 256, 0, stream>>>(pse, Gg, Ge4, gsum, PB, cB, aleS);
    k_ab<<<(Nn * 8 + 255) / 256, 256, 0, stream>>>(h, Bs, Bd, als, ald);

    // cooperative layer loop: grid sized for full residency
    int nbpc = 0;
    hipOccupancyMaxActiveBlocksPerMultiprocessor(&nbpc, k_loop, 256, 0);
    if (nbpc < 1) nbpc = 1;
    int grid = nbpc * 256;          // 256 CUs on MI355X
    if (grid > 2048) grid = 2048;
    const int2* pse_c = pse;
    const float4* aleS_c = aleS;
    const unsigned short* WsumT_c = WsumT;
    const int* seg_c = seg;
    void* args[] = {(void*)&pse_c, (void*)&seg_c, (void*)&als, (void*)&ald,
                    (void*)&aleS_c, (void*)&hb, (void*)&aggb, (void*)&WsumT_c,
                    (void*)&gb, (void*)&lnsc, (void*)&lnbi, (void*)&h,
                    (void*)&Bs, (void*)&Bd, (void*)&ow, (void*)&ob, (void*)&out};
    hipLaunchCooperativeKernel((const void*)k_loop, dim3(grid), dim3(256), args, 0, stream);
}

// Round 16
// 575.901 us; speedup vs baseline: 2.7701x; 2.7701x over previous
//
#include <hip/hip_runtime.h>
#include <hip/hip_bf16.h>
#include <math.h>

#define Nn 10000
#define Ee 160000
#define ET 170000   // Ee + Nn (self loops)
#define LL 6

typedef short v8s __attribute__((ext_vector_type(8)));
typedef float v4f __attribute__((ext_vector_type(4)));
typedef float v2f __attribute__((ext_vector_type(2)));

__device__ __forceinline__ unsigned short f2bf(float v) {
    unsigned int b = __float_as_uint(v);
    b += 0x7fffu + ((b >> 16) & 1u);   // RNE
    return (unsigned short)(b >> 16);
}
__device__ __forceinline__ float bflo(unsigned int u) { return __uint_as_float(u << 16); }
__device__ __forceinline__ float bfhi(unsigned int u) { return __uint_as_float(u & 0xffff0000u); }

// ---------------- node embedding ----------------
__global__ void k_node_embed(const float* __restrict__ x, const float* __restrict__ nw,
                             const float* __restrict__ nb, float* __restrict__ h,
                             unsigned short* __restrict__ hb) {
    int idx = blockIdx.x * 256 + threadIdx.x;
    if (idx >= Nn * 128) return;
    int n = idx >> 7, c = idx & 127;
    const float* xr = x + (size_t)n * 8;
    float acc = nb[c];
#pragma unroll
    for (int k = 0; k < 8; k++) acc += xr[k] * nw[k * 128 + c];
    h[idx] = acc;
    hb[idx] = f2bf(acc);
}

// ---------------- small precompute: E1 ----------------
__global__ void k_small(const float* __restrict__ vnfc, const float* __restrict__ vw,
                        const float* __restrict__ vb, const float* __restrict__ eab,
                        const float* __restrict__ a1w, const float* __restrict__ a1b,
                        const float* __restrict__ eaw, float* __restrict__ E1) {
    __shared__ float vr[128];
    __shared__ float sM1[512];
    __shared__ float sd1[128];
    int t = threadIdx.x;   // 512
    if (t < 128) {
        float a = vb[t];
#pragma unroll
        for (int k = 0; k < 6; k++) a += vnfc[k] * vw[k * 128 + t];
        vr[t] = a;
    }
    __syncthreads();
    if (t < 128) {
        float a = a1b[t];
        for (int k = 0; k < 128; k++) a += eab[k] * a1w[k * 128 + t];
        for (int k = 0; k < 128; k++) a += vr[k] * a1w[(128 + k) * 128 + t];
        sd1[t] = a;
    }
    {
        int r = t >> 7, j = t & 127;
        float a = 0.f;
        for (int k = 0; k < 128; k++) a += eaw[r * 128 + k] * a1w[k * 128 + j];
        sM1[r * 128 + j] = a;
    }
    __syncthreads();
    if (t < 128) {
        E1[t * 8 + 0] = sM1[t];
        E1[t * 8 + 1] = sM1[128 + t];
        E1[t * 8 + 2] = sM1[256 + t];
        E1[t * 8 + 3] = sM1[384 + t];
        E1[t * 8 + 4] = sd1[t];
        E1[t * 8 + 5] = 0.f; E1[t * 8 + 6] = 0.f; E1[t * 8 + 7] = 0.f;
    }
}

// ---------------- B matrices ----------------
__global__ void k_bmat(const float* __restrict__ glw, const float* __restrict__ gas,
                       const float* __restrict__ gad, const float* __restrict__ glew,
                       const float* __restrict__ gae, float* __restrict__ Bs,
                       float* __restrict__ Bd, float* __restrict__ Be) {
    int idx = blockIdx.x * 256 + threadIdx.x;
    if (idx >= LL * 128 * 4) return;
    int hh = idx & 3, k = (idx >> 2) & 127, l = idx >> 9;
    const float* lwp = glw  + (size_t)l * 65536 + k * 512 + hh * 128;
    const float* lep = glew + (size_t)l * 65536 + k * 512 + hh * 128;
    const float* sp = gas + l * 512 + hh * 128;
    const float* dp = gad + l * 512 + hh * 128;
    const float* ep = gae + l * 512 + hh * 128;
    float s1 = 0, s2 = 0, s3 = 0;
    for (int c = 0; c < 128; c++) {
        float lv = lwp[c];
        s1 += lv * sp[c];
        s2 += lv * dp[c];
        s3 += lep[c] * ep[c];
    }
    Bs[idx] = s1; Bd[idx] = s2; Be[idx] = s3;
}

// ---- WsumT[l][c][kk] bf16 = 0.25 * lw_l[kk&127][ (kk>>7)*128 + c ] ----
__global__ void k_wsum(const float* __restrict__ glw, unsigned short* __restrict__ WsumT) {
    int idx = blockIdx.x * 256 + threadIdx.x;
    if (idx >= LL * 128 * 512) return;
    int kk = idx & 511;
    int c = (idx >> 9) & 127;
    int l = idx >> 16;
    float v = 0.25f * glw[(size_t)l * 65536 + (size_t)(kk & 127) * 512 + (kk >> 7) * 128 + c];
    WsumT[(size_t)l * 65536 + (size_t)c * 512 + kk] = f2bf(v);
}

// ---------------- PB/cB ----------------
__global__ void k_pb(const float* __restrict__ eaw, const float* __restrict__ eab,
                     const float* __restrict__ Be, float* __restrict__ PB,
                     float* __restrict__ cB) {
    int t = threadIdx.x;
    if (t >= 24) return;
    int l = t >> 2, hh = t & 3;
    const float* bp = Be + l * 512 + hh;
    float s0 = 0, s1 = 0, s2 = 0, s3 = 0, sc = 0;
    for (int k = 0; k < 128; k++) {
        float bv = bp[k * 4];
        s0 += eaw[0 * 128 + k] * bv;
        s1 += eaw[1 * 128 + k] * bv;
        s2 += eaw[2 * 128 + k] * bv;
        s3 += eaw[3 * 128 + k] * bv;
        sc += eab[k] * bv;
    }
    PB[0 * 24 + t] = s0; PB[1 * 24 + t] = s1;
    PB[2 * 24 + t] = s2; PB[3 * 24 + t] = s3;
    cB[t] = sc;
}

// ---- edge gate MLP (R12-proven): 256 thr, 4 edges/lane ----
__global__ __launch_bounds__(256, 3) void k_edge(
    const float* __restrict__ ea, const float* __restrict__ E1,
    const float* __restrict__ a2w, const float* __restrict__ a2b,
    const float* __restrict__ a3w, const float* __restrict__ a3b,
    float* __restrict__ Gg, float4* __restrict__ Ge4, float* __restrict__ gsum) {
    __shared__ float sw2[128 * 64];
    __shared__ float4 sM[128];
    __shared__ float sD[128];
    __shared__ float prs[4][256];
    __shared__ float gsh[256];
    int t = threadIdx.x;
    int lane = t & 63;
    int p = t >> 6;
    int ps = __builtin_amdgcn_readfirstlane(p);
    for (int z = t; z < 2048; z += 256) ((float4*)sw2)[z] = ((const float4*)a2w)[z];
    if (t < 128) { sM[t] = *(const float4*)(E1 + t * 8); sD[t] = E1[t * 8 + 4]; }
    __syncthreads();
    int eb = blockIdx.x * 256 + lane;
    float4 ev[4];
#pragma unroll
    for (int r = 0; r < 4; r++) ev[r] = *(const float4*)(ea + (size_t)(eb + r * 64) * 4);
    v2f acc[4][8];
#pragma unroll
    for (int j = 0; j < 8; j++) {
        v2f b = {a2b[ps * 16 + 2 * j], a2b[ps * 16 + 2 * j + 1]};
#pragma unroll
        for (int r = 0; r < 4; r++) acc[r][j] = b;
    }
    const float* w2base = sw2 + ps * 16;
    for (int k = 0; k < 128; k++) {
        float4 m = sM[k];
        float dk = sD[k];
        v2f xx[4];
#pragma unroll
        for (int r = 0; r < 4; r++) {
            float xv = fmaxf(dk + ev[r].x * m.x + ev[r].y * m.y + ev[r].z * m.z + ev[r].w * m.w, 0.f);
            xx[r][0] = xv; xx[r][1] = xv;
        }
        const float* w2r = w2base + k * 64;
#pragma unroll
        for (int j4 = 0; j4 < 4; j4++) {
            float4 wv = *(const float4*)(w2r + j4 * 4);
            v2f w01 = {wv.x, wv.y}, w23 = {wv.z, wv.w};
#pragma unroll
            for (int r = 0; r < 4; r++) {
                acc[r][2 * j4]     += xx[r] * w01;
                acc[r][2 * j4 + 1] += xx[r] * w23;
            }
        }
    }
#pragma unroll
    for (int r = 0; r < 4; r++) {
        float pr = 0.f;
#pragma unroll
        for (int j = 0; j < 8; j++) {
            pr += fmaxf(acc[r][j][0], 0.f) * a3w[ps * 16 + 2 * j];
            pr += fmaxf(acc[r][j][1], 0.f) * a3w[ps * 16 + 2 * j + 1];
        }
        prs[p][r * 64 + lane] = pr;
    }
    __syncthreads();
    if (p == 0) {
        float v0 = 0.f, v1 = 0.f, v2 = 0.f, v3 = 0.f, v4 = 0.f;
#pragma unroll
        for (int rep = 0; rep < 4; rep++) {
            int le = rep * 64 + lane;
            float tot = prs[0][le] + prs[1][le] + prs[2][le] + prs[3][le] + a3b[0];
            float g = 1.f / (1.f + __expf(-tot));
            gsh[le] = g;
            float4 evv = ev[rep];
            v0 += g; v1 += g * evv.x; v2 += g * evv.y; v3 += g * evv.z; v4 += g * evv.w;
        }
#pragma unroll
        for (int d = 32; d > 0; d >>= 1) {
            v0 += __shfl_down(v0, d); v1 += __shfl_down(v1, d); v2 += __shfl_down(v2, d);
            v3 += __shfl_down(v3, d); v4 += __shfl_down(v4, d);
        }
        if (lane == 0) {
            atomicAdd(&gsum[0], v0); atomicAdd(&gsum[1], v1); atomicAdd(&gsum[2], v2);
            atomicAdd(&gsum[3], v3); atomicAdd(&gsum[4], v4);
        }
    }
    __syncthreads();
    {
        int e = blockIdx.x * 256 + ps * 64 + lane;
        float g = gsh[ps * 64 + lane];
        float4 evv = *(const float4*)(ea + (size_t)e * 4);
        Gg[e] = g;
        Ge4[e] = make_float4(g * evv.x, g * evv.y, g * evv.z, g * evv.w);
    }
}

// ---------------- counting sort: hist / scan / scatter ----------------
__global__ void k_hist(const int* __restrict__ ei, int* __restrict__ hist) {
    int i = blockIdx.x * 256 + threadIdx.x;
    if (i >= ET) return;
    int d = (i < Ee) ? ei[Ee + i] : (i - Ee);
    atomicAdd(&hist[d], 1);
}

__global__ __launch_bounds__(1024) void k_scan(const int* __restrict__ hist,
                                               int* __restrict__ seg, int* __restrict__ pos) {
    __shared__ int wsums[16];
    __shared__ int carry_s;
    int t = threadIdx.x;
    int lane = t & 63, wid = t >> 6;
    if (t == 0) { carry_s = 0; seg[0] = 0; }
    __syncthreads();
    for (int base = 0; base < Nn; base += 1024) {
        int idx = base + t;
        int v = (idx < Nn) ? hist[idx] : 0;
        int sc = v;
#pragma unroll
        for (int d = 1; d < 64; d <<= 1) {
            int up = __shfl_up(sc, d);
            if (lane >= d) sc += up;
        }
        if (lane == 63) wsums[wid] = sc;
        __syncthreads();
        if (wid == 0) {
            int wv = (lane < 16) ? wsums[lane] : 0;
            int wsc = wv;
#pragma unroll
            for (int d = 1; d < 16; d <<= 1) {
                int up = __shfl_up(wsc, d);
                if (lane >= d) wsc += up;
            }
            if (lane < 16) wsums[lane] = wsc - wv;
        }
        __syncthreads();
        int carry = carry_s;
        int inc = sc + wsums[wid] + carry;
        if (idx < Nn) { seg[idx + 1] = inc; pos[idx] = inc - v; }
        __syncthreads();
        if (t == 1023) carry_s = inc;
        __syncthreads();
    }
}

__global__ void k_scatter(const int* __restrict__ ei, int* __restrict__ pos,
                          int2* __restrict__ pse) {
    int i = blockIdx.x * 256 + threadIdx.x;
    if (i >= ET) return;
    int s, d;
    if (i < Ee) { s = ei[i]; d = ei[Ee + i]; } else { s = d = i - Ee; }
    int idx = atomicAdd(&pos[d], 1);
    pse[idx] = make_int2(s, i);
}

// ---- aleS[l][i] (sorted order, all layers) ----
__global__ void k_ales(const int2* __restrict__ pse, const float* __restrict__ Gg,
                       const float4* __restrict__ Ge4, const float* __restrict__ gsum,
                       const float* __restrict__ PB, const float* __restrict__ cB,
                       float4* __restrict__ aleS) {
    int i = blockIdx.x * 256 + threadIdx.x;
    if (i >= ET) return;
    int y = pse[i].y;
    float g;
    float4 ge;
    if (y < Ee) { g = Gg[y]; ge = Ge4[y]; }
    else {
        float inv = 1.f / Ee;
        g = gsum[0] * inv;
        ge = make_float4(gsum[1] * inv, gsum[2] * inv, gsum[3] * inv, gsum[4] * inv);
    }
#pragma unroll
    for (int l = 0; l < LL; l++) {
        float4 o;
        o.x = g * cB[l * 4 + 0] + ge.x * PB[0 * 24 + l * 4 + 0] + ge.y * PB[1 * 24 + l * 4 + 0]
            + ge.z * PB[2 * 24 + l * 4 + 0] + ge.w * PB[3 * 24 + l * 4 + 0];
        o.y = g * cB[l * 4 + 1] + ge.x * PB[0 * 24 + l * 4 + 1] + ge.y * PB[1 * 24 + l * 4 + 1]
            + ge.z * PB[2 * 24 + l * 4 + 1] + ge.w * PB[3 * 24 + l * 4 + 1];
        o.z = g * cB[l * 4 + 2] + ge.x * PB[0 * 24 + l * 4 + 2] + ge.y * PB[1 * 24 + l * 4 + 2]
            + ge.z * PB[2 * 24 + l * 4 + 2] + ge.w * PB[3 * 24 + l * 4 + 2];
        o.w = g * cB[l * 4 + 3] + ge.x * PB[0 * 24 + l * 4 + 3] + ge.y * PB[1 * 24 + l * 4 + 3]
            + ge.z * PB[2 * 24 + l * 4 + 3] + ge.w * PB[3 * 24 + l * 4 + 3];
        aleS[(size_t)l * ET + i] = o;
    }
}

// ---------------- layer-0: als/ald ----------------
__global__ void k_ab(const float* __restrict__ h, const float* __restrict__ Bs_l,
                     const float* __restrict__ Bd_l, float* __restrict__ als,
                     float* __restrict__ ald) {
    int idx = blockIdx.x * 256 + threadIdx.x;
    if (idx >= Nn * 8) return;
    int n = idx >> 3, slot = idx & 7;
    const float* B = (slot < 4) ? Bs_l : Bd_l;
    int hh = slot & 3;
    const float4* hr = (const float4*)(h + (size_t)n * 128);
    float s = 0.f;
#pragma unroll 8
    for (int kb = 0; kb < 32; kb++) {
        float4 hv = hr[kb];
        s += hv.x * B[(4 * kb + 0) * 4 + hh] + hv.y * B[(4 * kb + 1) * 4 + hh]
           + hv.z * B[(4 * kb + 2) * 4 + hh] + hv.w * B[(4 * kb + 3) * 4 + hh];
    }
    if (slot < 4) als[n * 4 + hh] = s;
    else          ald[n * 4 + hh] = s;
}

// ==== fused per-layer kernel: block owns 16 nodes; agg (LDS aggb) -> post ====
// reads hb_r/als_r/ald_r (buffer A), writes hb_w/als_w/ald_w (buffer B); h in place.
#define AGS 520   // padded aggb row stride (shorts) to avoid 16-way LDS conflicts
__global__ __launch_bounds__(256) void k_layer(
    const int2* __restrict__ pse, const int* __restrict__ seg,
    const float* __restrict__ als_r, const float* __restrict__ ald_r,
    float* __restrict__ als_w, float* __restrict__ ald_w,
    const float4* __restrict__ aleS_l,
    const unsigned short* __restrict__ hb_r, unsigned short* __restrict__ hb_w,
    const unsigned short* __restrict__ WsumT_l,
    const float* __restrict__ gbias, const float* __restrict__ ls,
    const float* __restrict__ lb, float* __restrict__ h,
    const float* __restrict__ Bs_n, const float* __restrict__ Bd_n) {
    __shared__ unsigned short saggb[16 * AGS];   // 16.25 KB
    __shared__ float sred1[64], sred2[64];
    __shared__ float sA[256], sDd[256];
    int t = threadIdx.x;
    int lane = t & 63;
    int w4 = t >> 6;
    int n0 = blockIdx.x * 16;
    int hp = lane >> 4;
    int cch = (lane & 15) * 8;
    // ---- phase A: each wave aggregates 4 nodes (full wave per node) ----
#pragma unroll
    for (int j = 0; j < 4; j++) {
        int n = n0 + w4 * 4 + j;
        int start = seg[n], end = seg[n + 1];
        float aldh = ald_r[n * 4 + hp];
        float den = 0.f;
        float4 acc0 = make_float4(0.f, 0.f, 0.f, 0.f);
        float4 acc1 = make_float4(0.f, 0.f, 0.f, 0.f);
        int i = start;
        for (; i + 2 <= end; i += 2) {
            int sa = pse[i].x, sb = pse[i + 1].x;
            float4 ala4 = aleS_l[i], alb4 = aleS_l[i + 1];
            float ala = hp == 0 ? ala4.x : hp == 1 ? ala4.y : hp == 2 ? ala4.z : ala4.w;
            float alb = hp == 0 ? alb4.x : hp == 1 ? alb4.y : hp == 2 ? alb4.z : alb4.w;
            float ava = als_r[sa * 4 + hp] + aldh + ala;
            float avb = als_r[sb * 4 + hp] + aldh + alb;
            ava = ava > 0.f ? ava : 0.2f * ava;
            avb = avb > 0.f ? avb : 0.2f * avb;
            float ea = __expf(fminf(ava, 60.f));
            float eb = __expf(fminf(avb, 60.f));
            den += ea + eb;
            uint4 ua = *(const uint4*)(hb_r + (size_t)sa * 128 + cch);
            uint4 ub = *(const uint4*)(hb_r + (size_t)sb * 128 + cch);
            acc0.x += ea * bflo(ua.x) + eb * bflo(ub.x);
            acc0.y += ea * bfhi(ua.x) + eb * bfhi(ub.x);
            acc0.z += ea * bflo(ua.y) + eb * bflo(ub.y);
            acc0.w += ea * bfhi(ua.y) + eb * bfhi(ub.y);
            acc1.x += ea * bflo(ua.z) + eb * bflo(ub.z);
            acc1.y += ea * bfhi(ua.z) + eb * bfhi(ub.z);
            acc1.z += ea * bflo(ua.w) + eb * bflo(ub.w);
            acc1.w += ea * bfhi(ua.w) + eb * bfhi(ub.w);
        }
        if (i < end) {
            int sa = pse[i].x;
            float4 ala4 = aleS_l[i];
            float ala = hp == 0 ? ala4.x : hp == 1 ? ala4.y : hp == 2 ? ala4.z : ala4.w;
            float ava = als_r[sa * 4 + hp] + aldh + ala;
            ava = ava > 0.f ? ava : 0.2f * ava;
            float ea = __expf(fminf(ava, 60.f));
            den += ea;
            uint4 ua = *(const uint4*)(hb_r + (size_t)sa * 128 + cch);
            acc0.x += ea * bflo(ua.x); acc0.y += ea * bfhi(ua.x);
            acc0.z += ea * bflo(ua.y); acc0.w += ea * bfhi(ua.y);
            acc1.x += ea * bflo(ua.z); acc1.y += ea * bfhi(ua.z);
            acc1.z += ea * bflo(ua.w); acc1.w += ea * bfhi(ua.w);
        }
        float inv = 1.f / (den + 1e-16f);
        ushort4 q0, q1;
        q0.x = f2bf(acc0.x * inv); q0.y = f2bf(acc0.y * inv);
        q0.z = f2bf(acc0.z * inv); q0.w = f2bf(acc0.w * inv);
        q1.x = f2bf(acc1.x * inv); q1.y = f2bf(acc1.y * inv);
        q1.z = f2bf(acc1.z * inv); q1.w = f2bf(acc1.w * inv);
        int r = w4 * 4 + j;
        *(ushort4*)&saggb[r * AGS + lane * 8] = q0;
        *(ushort4*)&saggb[r * AGS + lane * 8 + 4] = q1;
    }
    __syncthreads();
    // ---- phase B: MFMA post on the LDS tile ----
    int m = lane & 15, q = lane >> 4;
    v4f accv[2];
    accv[0] = (v4f){0.f, 0.f, 0.f, 0.f};
    accv[1] = (v4f){0.f, 0.f, 0.f, 0.f};
    const unsigned short* arow = &saggb[m * AGS + q * 8];
    int col0 = (2 * w4) * 16 + m, col1 = col0 + 16;
#pragma unroll 4
    for (int ks = 0; ks < 16; ks++) {
        v8s fa = *(const v8s*)(arow + ks * 32);
        v8s fb0 = *(const v8s*)(WsumT_l + (size_t)col0 * 512 + ks * 32 + q * 8);
        v8s fb1 = *(const v8s*)(WsumT_l + (size_t)col1 * 512 + ks * 32 + q * 8);
        accv[0] = __builtin_amdgcn_mfma_f32_16x16x32_bf16(fa, fb0, accv[0], 0, 0, 0);
        accv[1] = __builtin_amdgcn_mfma_f32_16x16x32_bf16(fa, fb1, accv[1], 0, 0, 0);
    }
    float v[2][4];
    float s1[4] = {0.f, 0.f, 0.f, 0.f}, s2[4] = {0.f, 0.f, 0.f, 0.f};
#pragma unroll
    for (int j = 0; j < 2; j++) {
        int col = j == 0 ? col0 : col1;
        float b = gbias[col];
#pragma unroll
        for (int r = 0; r < 4; r++) {
            int row = n0 + q * 4 + r;
            float val = h[(size_t)row * 128 + col] + fmaxf(accv[j][r] + b, 0.f);
            v[j][r] = val;
            s1[r] += val; s2[r] += val * val;
        }
    }
#pragma unroll
    for (int d = 1; d <= 8; d <<= 1) {
#pragma unroll
        for (int r = 0; r < 4; r++) {
            s1[r] += __shfl_xor(s1[r], d);
            s2[r] += __shfl_xor(s2[r], d);
        }
    }
    if (m == 0) {
#pragma unroll
        for (int r = 0; r < 4; r++) {
            sred1[w4 * 16 + q * 4 + r] = s1[r];
            sred2[w4 * 16 + q * 4 + r] = s2[r];
        }
    }
    __syncthreads();
    float o2[2][4];
#pragma unroll
    for (int r = 0; r < 4; r++) {
        int row = q * 4 + r;
        float t1 = sred1[row] + sred1[16 + row] + sred1[32 + row] + sred1[48 + row];
        float t2 = sred2[row] + sred2[16 + row] + sred2[32 + row] + sred2[48 + row];
        float mean = t1 * (1.f / 128.f);
        float var = t2 * (1.f / 128.f) - mean * mean;
        float rinv = rsqrtf(var + 1e-5f);
        int grow = n0 + row;
#pragma unroll
        for (int j = 0; j < 2; j++) {
            int col = j == 0 ? col0 : col1;
            float o = (v[j][r] - mean) * rinv * ls[col] + lb[col];
            o2[j][r] = o;
            h[(size_t)grow * 128 + col] = o;
            hb_w[(size_t)grow * 128 + col] = f2bf(o);
        }
    }
    float sal[4][4], sad[4][4];
#pragma unroll
    for (int r = 0; r < 4; r++)
#pragma unroll
        for (int hh = 0; hh < 4; hh++) { sal[r][hh] = 0.f; sad[r][hh] = 0.f; }
#pragma unroll
    for (int j = 0; j < 2; j++) {
        int col = j == 0 ? col0 : col1;
        float4 bs = *(const float4*)(Bs_n + col * 4);
        float4 bd = *(const float4*)(Bd_n + col * 4);
#pragma unroll
        for (int r = 0; r < 4; r++) {
            float o = o2[j][r];
            sal[r][0] += o * bs.x; sal[r][1] += o * bs.y;
            sal[r][2] += o * bs.z; sal[r][3] += o * bs.w;
            sad[r][0] += o * bd.x; sad[r][1] += o * bd.y;
            sad[r][2] += o * bd.z; sad[r][3] += o * bd.w;
        }
    }
#pragma unroll
    for (int d = 1; d <= 8; d <<= 1) {
#pragma unroll
        for (int r = 0; r < 4; r++)
#pragma unroll
            for (int hh = 0; hh < 4; hh++) {
                sal[r][hh] += __shfl_xor(sal[r][hh], d);
                sad[r][hh] += __shfl_xor(sad[r][hh], d);
            }
    }
    if (m == 0) {
#pragma unroll
        for (int r = 0; r < 4; r++)
#pragma unroll
            for (int hh = 0; hh < 4; hh++) {
                sA[w4 * 64 + (q * 4 + r) * 4 + hh] = sal[r][hh];
                sDd[w4 * 64 + (q * 4 + r) * 4 + hh] = sad[r][hh];
            }
    }
    __syncthreads();
    if (t < 128) {
        int row = t >> 3, slot = t & 7, hh = slot & 3;
        if (slot < 4) {
            float va = sA[row * 4 + hh] + sA[64 + row * 4 + hh]
                     + sA[128 + row * 4 + hh] + sA[192 + row * 4 + hh];
            als_w[(n0 + row) * 4 + hh] = va;
        } else {
            float vd = sDd[row * 4 + hh] + sDd[64 + row * 4 + hh]
                     + sDd[128 + row * 4 + hh] + sDd[192 + row * 4 + hh];
            ald_w[(n0 + row) * 4 + hh] = vd;
        }
    }
}

// ---------------- output projection ----------------
__global__ __launch_bounds__(256) void k_out(
    const float* __restrict__ h, const float* __restrict__ ow,
    const float* __restrict__ ob, float* __restrict__ out) {
    __shared__ float4 hs4[8][32];
    int t = threadIdx.x;
    int n0 = blockIdx.x * 8;
    if (t < 256) {
        int i = t >> 5, kb = t & 31;
        hs4[i][kb] = *(const float4*)(h + (size_t)(n0 + i) * 128 + 4 * kb);
    }
    __syncthreads();
    float acc[8] = {0, 0, 0, 0, 0, 0, 0, 0};
    for (int kb = 0; kb < 32; kb++) {
        float w0 = ow[(4 * kb + 0) * 256 + t];
        float w1 = ow[(4 * kb + 1) * 256 + t];
        float w2 = ow[(4 * kb + 2) * 256 + t];
        float w3 = ow[(4 * kb + 3) * 256 + t];
#pragma unroll
        for (int i = 0; i < 8; i++) {
            float4 hv = hs4[i][kb];
            acc[i] += hv.x * w0 + hv.y * w1 + hv.z * w2 + hv.w * w3;
        }
    }
    float b = ob[t];
#pragma unroll
    for (int i = 0; i < 8; i++) out[(size_t)(n0 + i) * 256 + t] = acc[i] + b;
}

extern "C" void kernel_launch(void* const* d_in, const int* in_sizes, int n_in,
                              void* d_out, int out_size, void* d_ws, size_t ws_size,
                              hipStream_t stream) {
    const float* x    = (const float*)d_in[0];
    const int*   ei   = (const int*)d_in[1];
    const float* ea   = (const float*)d_in[2];
    const float* vnfc = (const float*)d_in[3];
    const float* nw   = (const float*)d_in[4];
    const float* nb   = (const float*)d_in[5];
    const float* eaw  = (const float*)d_in[6];
    const float* eab  = (const float*)d_in[7];
    const float* vw   = (const float*)d_in[8];
    const float* vb   = (const float*)d_in[9];
    const float* a1w  = (const float*)d_in[10];
    const float* a1b  = (const float*)d_in[11];
    const float* a2w  = (const float*)d_in[12];
    const float* a2b  = (const float*)d_in[13];
    const float* a3w  = (const float*)d_in[14];
    const float* a3b  = (const float*)d_in[15];
    const float* glw  = (const float*)d_in[16];
    const float* gas  = (const float*)d_in[17];
    const float* gad  = (const float*)d_in[18];
    const float* glew = (const float*)d_in[19];
    const float* gae  = (const float*)d_in[20];
    const float* gb   = (const float*)d_in[21];
    const float* lnsc = (const float*)d_in[22];
    const float* lnbi = (const float*)d_in[23];
    const float* ow   = (const float*)d_in[24];
    const float* ob   = (const float*)d_in[25];
    float* out = (float*)d_out;

    char* w = (char*)d_ws;
    size_t o = 0;
    auto allocf = [&](size_t cnt) { float* p = (float*)(w + o); o += ((cnt * 4 + 255) / 256) * 256; return p; };
    auto alloci = [&](size_t cnt) { int* p = (int*)(w + o); o += ((cnt * 4 + 255) / 256) * 256; return p; };
    auto allocu = [&](size_t cnt) { unsigned short* p = (unsigned short*)(w + o); o += ((cnt * 2 + 255) / 256) * 256; return p; };
    float* h      = allocf((size_t)Nn * 128);
    unsigned short* hb0 = allocu((size_t)Nn * 128);
    unsigned short* hb1 = allocu((size_t)Nn * 128);
    unsigned short* WsumT = allocu((size_t)LL * 128 * 512);
    float* als0 = allocf((size_t)Nn * 4);
    float* ald0 = allocf((size_t)Nn * 4);
    float* als1 = allocf((size_t)Nn * 4);
    float* ald1 = allocf((size_t)Nn * 4);
    float* Gg   = allocf((size_t)Ee);
    float4* Ge4 = (float4*)allocf((size_t)Ee * 4);
    float4* aleS = (float4*)allocf((size_t)LL * ET * 4);
    float* Bs   = allocf(3072);
    float* Bd   = allocf(3072);
    float* Be   = allocf(3072);
    float* E1   = allocf(1024);
    float* PB   = allocf(96);
    float* cB   = allocf(24);
    float* gsum = allocf(8);
    int* seg  = alloci(Nn + 1);
    int* hist = alloci(Nn);
    int* pos  = alloci(Nn);
    int2* pse = (int2*)alloci((size_t)ET * 2);

    hipMemsetAsync(hist, 0, Nn * sizeof(int), stream);
    hipMemsetAsync(gsum, 0, 8 * sizeof(float), stream);

    k_node_embed<<<(Nn * 128 + 255) / 256, 256, 0, stream>>>(x, nw, nb, h, hb0);
    k_small<<<1, 512, 0, stream>>>(vnfc, vw, vb, eab, a1w, a1b, eaw, E1);
    k_bmat<<<(LL * 128 * 4 + 255) / 256, 256, 0, stream>>>(glw, gas, gad, glew, gae, Bs, Bd, Be);
    k_wsum<<<(LL * 128 * 512 + 255) / 256, 256, 0, stream>>>(glw, WsumT);
    k_pb<<<1, 32, 0, stream>>>(eaw, eab, Be, PB, cB);
    k_edge<<<Ee / 256, 256, 0, stream>>>(ea, E1, a2w, a2b, a3w, a3b, Gg, Ge4, gsum);
    k_hist<<<(ET + 255) / 256, 256, 0, stream>>>(ei, hist);
    k_scan<<<1, 1024, 0, stream>>>(hist, seg, pos);
    k_scatter<<<(ET + 255) / 256, 256, 0, stream>>>(ei, pos, pse);
    k_ales<<<(ET + 255) / 256, 256, 0, stream>>>(pse, Gg, Ge4, gsum, PB, cB, aleS);
    k_ab<<<(Nn * 8 + 255) / 256, 256, 0, stream>>>(h, Bs, Bd, als0, ald0);

    unsigned short* hbb[2] = {hb0, hb1};
    float* alsb[2] = {als0, als1};
    float* aldb[2] = {ald0, ald1};
    for (int l = 0; l < LL; l++) {
        int ci = l & 1, ni = 1 - ci;
        int ln = (l + 1) % LL;
        k_layer<<<Nn / 16, 256, 0, stream>>>(
            pse, seg, alsb[ci], aldb[ci], alsb[ni], aldb[ni],
            aleS + (size_t)l * ET, hbb[ci], hbb[ni],
            WsumT + (size_t)l * 65536, gb + l * 128, lnsc + l * 128, lnbi + l * 128,
            h, Bs + ln * 512, Bd + ln * 512);
    }
    k_out<<<Nn / 8, 256, 0, stream>>>(h, ow, ob, out);
}